// Round 1
// baseline (161.643 us; speedup 1.0000x reference)
//
#include <hip/hip_runtime.h>

typedef __attribute__((ext_vector_type(8))) short bf16x8;
typedef __attribute__((ext_vector_type(4))) short bf16x4;
typedef __attribute__((ext_vector_type(4))) float f32x4;
typedef __attribute__((ext_vector_type(4))) float floatx4;

__device__ __forceinline__ unsigned short f2bf(float f) {
    unsigned int u = __float_as_uint(f);
    u += 0x7fffu + ((u >> 16) & 1u);   // round-to-nearest-even
    return (unsigned short)(u >> 16);
}
__device__ __forceinline__ float bf2f_s(short h) {
    return __uint_as_float(((unsigned int)(unsigned short)h) << 16);
}

// ---------------- kernel 0: weight conversion to bf16 ----------------
// Wkvb[256][1024]: rows 0-127 = Wk, rows 128-255 = Wv.  Wob[1024][128] = Wo.
__global__ void k_convert(const float* __restrict__ Wk, const float* __restrict__ Wv,
                          const float* __restrict__ Wo,
                          unsigned short* __restrict__ Wkvb, unsigned short* __restrict__ Wob) {
    int i = blockIdx.x * blockDim.x + threadIdx.x;
    if (i < 131072) {
        Wkvb[i]          = f2bf(Wk[i]);
        Wkvb[131072 + i] = f2bf(Wv[i]);
        Wob[i]           = f2bf(Wo[i]);
    }
}

// ---------------- kernel 1: keys/vals GEMM ----------------
// kv[m][n] = sum_e patches[m][e] * Wkvb[n][e]  (+ patch_pos bias for n<128)
// m = b*196 + kpatch in [0,50176), n in [0,256). Tiles 64(M) x 256(N), BK=64.
__global__ __launch_bounds__(512)
void k_keysvals(const float* __restrict__ patches,
                const unsigned short* __restrict__ Wkvb,
                const float* __restrict__ patch_pos,
                unsigned short* __restrict__ kv)
{
    __shared__ unsigned short As[64][72];    // +8 pad: spreads banks for frag reads
    __shared__ unsigned short Bs[256][72];

    const int tid  = threadIdx.x;
    const int lane = tid & 63;
    const int wave = tid >> 6;      // 0..7
    const int wm   = wave >> 2;     // 0..1  (32-row half)
    const int wn   = wave & 3;      // 0..3  (64-col quarter)
    const int l15  = lane & 15;
    const int lg   = lane >> 4;     // 0..3
    const int row0 = blockIdx.x * 64;

    f32x4 acc[2][4];
    #pragma unroll
    for (int i = 0; i < 2; ++i)
        #pragma unroll
        for (int j = 0; j < 4; ++j)
            acc[i][j] = (f32x4){0.f, 0.f, 0.f, 0.f};

    for (int ko = 0; ko < 1024; ko += 64) {
        // stage A: 64x64 f32 -> bf16 (reg-staged: need the f32->bf16 convert)
        {
            int r = tid >> 4;            // 0..31
            int c = (tid & 15) * 4;      // 0..60
            #pragma unroll
            for (int it = 0; it < 2; ++it) {
                floatx4 v = *reinterpret_cast<const floatx4*>(
                    patches + (size_t)(row0 + it * 32 + r) * 1024 + ko + c);
                bf16x4 sv;
                sv[0] = (short)f2bf(v[0]); sv[1] = (short)f2bf(v[1]);
                sv[2] = (short)f2bf(v[2]); sv[3] = (short)f2bf(v[3]);
                *reinterpret_cast<bf16x4*>(&As[it * 32 + r][c]) = sv;
            }
        }
        // stage B: 256x64 bf16 straight copy
        {
            int r = tid >> 3;            // 0..63
            int c = (tid & 7) * 8;       // 0..56
            #pragma unroll
            for (int it = 0; it < 4; ++it) {
                bf16x8 v = *reinterpret_cast<const bf16x8*>(
                    Wkvb + (size_t)(it * 64 + r) * 1024 + ko + c);
                *reinterpret_cast<bf16x8*>(&Bs[it * 64 + r][c]) = v;
            }
        }
        __syncthreads();
        #pragma unroll
        for (int kk = 0; kk < 2; ++kk) {
            bf16x8 af[2], bfr[4];
            #pragma unroll
            for (int mi = 0; mi < 2; ++mi)
                af[mi] = *reinterpret_cast<const bf16x8*>(&As[wm * 32 + mi * 16 + l15][kk * 32 + lg * 8]);
            #pragma unroll
            for (int ni = 0; ni < 4; ++ni)
                bfr[ni] = *reinterpret_cast<const bf16x8*>(&Bs[wn * 64 + ni * 16 + l15][kk * 32 + lg * 8]);
            #pragma unroll
            for (int mi = 0; mi < 2; ++mi)
                #pragma unroll
                for (int ni = 0; ni < 4; ++ni)
                    acc[mi][ni] = __builtin_amdgcn_mfma_f32_16x16x32_bf16(af[mi], bfr[ni], acc[mi][ni], 0, 0, 0);
        }
        __syncthreads();
    }
    // epilogue: C/D layout col=lane&15, row=(lane>>4)*4+reg  [verified]
    #pragma unroll
    for (int mi = 0; mi < 2; ++mi) {
        #pragma unroll
        for (int i = 0; i < 4; ++i) {
            int m  = row0 + wm * 32 + mi * 16 + lg * 4 + i;
            int kp = m % 196;
            #pragma unroll
            for (int ni = 0; ni < 4; ++ni) {
                int n = wn * 64 + ni * 16 + l15;
                float v = acc[mi][ni][i];
                if (n < 128) v += patch_pos[kp * 128 + n];
                kv[(size_t)m * 256 + n] = f2bf(v);
            }
        }
    }
}

// ---------------- kernel 2: per-batch attention ----------------
__global__ __launch_bounds__(1024)
void k_attn(const unsigned short* __restrict__ kv,
            const float* __restrict__ queries,
            const float* __restrict__ prior,
            const float* __restrict__ temperature,
            float* __restrict__ attn_out,
            unsigned short* __restrict__ att)
{
    __shared__ unsigned short k_s[196][136];  // padded: lane-consecutive row reads spread banks
    __shared__ unsigned short v_s[196][128];
    __shared__ unsigned short q_s[52][128];
    __shared__ float          l_s[52][196];

    const int b   = blockIdx.x;
    const int tid = threadIdx.x;
    const size_t base = (size_t)b * 196 * 256;

    // stage K and V (bf16) from kv rows
    for (int idx = tid; idx < 6272; idx += 1024) {
        int row = idx >> 5;
        int c   = (idx & 31) * 8;
        bf16x8 v = *reinterpret_cast<const bf16x8*>(kv + base + row * 256 + c);
        if (c < 128) *reinterpret_cast<bf16x8*>(&k_s[row][c])       = v;
        else         *reinterpret_cast<bf16x8*>(&v_s[row][c - 128]) = v;
    }
    // stage Q (f32 -> bf16)
    for (int idx = tid; idx < 1664; idx += 1024) {
        int row = idx >> 5;
        int c   = (idx & 31) * 4;
        const float* qp = queries + row * 128 + c;
        bf16x4 sv;
        sv[0] = (short)f2bf(qp[0]); sv[1] = (short)f2bf(qp[1]);
        sv[2] = (short)f2bf(qp[2]); sv[3] = (short)f2bf(qp[3]);
        *reinterpret_cast<bf16x4*>(&q_s[row][c]) = sv;
    }
    __syncthreads();

    const float inv_temp  = 1.0f / (log1pf(expf(temperature[0])) + 0.5f);
    const float inv_scale = 0.08838834764831845f;  // 1/sqrt(128)

    // logits: task = (q, kg), kg in [0,49); each handles k = kg + 49*j
    for (int task = tid; task < 3328; task += 1024) {
        int q  = task >> 6;      // uniform per wave -> q_s reads broadcast
        int kg = task & 63;
        if (kg < 49) {
            float dot0 = 0.f, dot1 = 0.f, dot2 = 0.f, dot3 = 0.f;
            #pragma unroll 4
            for (int c = 0; c < 128; c += 8) {
                bf16x8 qv = *reinterpret_cast<const bf16x8*>(&q_s[q][c]);
                float qf[8];
                #pragma unroll
                for (int e = 0; e < 8; ++e) qf[e] = bf2f_s(qv[e]);
                bf16x8 k0v = *reinterpret_cast<const bf16x8*>(&k_s[kg][c]);
                bf16x8 k1v = *reinterpret_cast<const bf16x8*>(&k_s[kg + 49][c]);
                bf16x8 k2v = *reinterpret_cast<const bf16x8*>(&k_s[kg + 98][c]);
                bf16x8 k3v = *reinterpret_cast<const bf16x8*>(&k_s[kg + 147][c]);
                #pragma unroll
                for (int e = 0; e < 8; ++e) {
                    dot0 += qf[e] * bf2f_s(k0v[e]);
                    dot1 += qf[e] * bf2f_s(k1v[e]);
                    dot2 += qf[e] * bf2f_s(k2v[e]);
                    dot3 += qf[e] * bf2f_s(k3v[e]);
                }
            }
            int k;
            k = kg;       l_s[q][k] = (dot0 * inv_scale + prior[q * 196 + k]) * inv_temp;
            k = kg + 49;  l_s[q][k] = (dot1 * inv_scale + prior[q * 196 + k]) * inv_temp;
            k = kg + 98;  l_s[q][k] = (dot2 * inv_scale + prior[q * 196 + k]) * inv_temp;
            k = kg + 147; l_s[q][k] = (dot3 * inv_scale + prior[q * 196 + k]) * inv_temp;
        }
    }
    __syncthreads();

    // softmax: one wave per q-row
    const int lane = tid & 63;
    const int wave = tid >> 6;
    for (int q = wave; q < 52; q += 16) {
        float x0 = l_s[q][lane];
        float x1 = l_s[q][lane + 64];
        float x2 = l_s[q][lane + 128];
        float x3 = (lane < 4) ? l_s[q][lane + 192] : -1e30f;
        float m = fmaxf(fmaxf(x0, x1), fmaxf(x2, x3));
        #pragma unroll
        for (int off = 32; off > 0; off >>= 1) m = fmaxf(m, __shfl_xor(m, off));
        float e0 = expf(x0 - m), e1 = expf(x1 - m), e2 = expf(x2 - m);
        float e3 = (lane < 4) ? expf(x3 - m) : 0.0f;
        float s = e0 + e1 + e2 + e3;
        #pragma unroll
        for (int off = 32; off > 0; off >>= 1) s += __shfl_xor(s, off);
        float inv = 1.0f / s;
        float* po = attn_out + ((size_t)b * 52 + q) * 196;
        float a0 = e0 * inv, a1 = e1 * inv, a2 = e2 * inv;
        l_s[q][lane]       = a0;  po[lane]       = a0;
        l_s[q][lane + 64]  = a1;  po[lane + 64]  = a1;
        l_s[q][lane + 128] = a2;  po[lane + 128] = a2;
        if (lane < 4) { float a3 = e3 * inv; l_s[q][lane + 192] = a3; po[lane + 192] = a3; }
    }
    __syncthreads();

    // attended[q][a] = sum_k attn[q][k] * v[k][a]  -> bf16 to ws
    if (tid < 832) {
        int q  = tid >> 4;
        int a0 = (tid & 15) * 8;
        float accv[8] = {0.f, 0.f, 0.f, 0.f, 0.f, 0.f, 0.f, 0.f};
        for (int k = 0; k < 196; ++k) {
            float w = l_s[q][k];
            bf16x8 vv = *reinterpret_cast<const bf16x8*>(&v_s[k][a0]);
            #pragma unroll
            for (int e = 0; e < 8; ++e) accv[e] += w * bf2f_s(vv[e]);
        }
        bf16x8 sv;
        #pragma unroll
        for (int e = 0; e < 8; ++e) sv[e] = (short)f2bf(accv[e]);
        *reinterpret_cast<bf16x8*>(att + ((size_t)b * 52 + q) * 128 + a0) = sv;
    }
}

// ---------------- kernel 3: output GEMM ----------------
// out[m][e] = sum_a att[m][a] * Wob[e][a] + bo[e],  m in [0,13312), e in [0,1024)
__global__ __launch_bounds__(512)
void k_out(const unsigned short* __restrict__ att,
           const unsigned short* __restrict__ Wob,
           const float* __restrict__ bo,
           float* __restrict__ out)
{
    __shared__ unsigned short As[64][72];
    __shared__ unsigned short Bs[256][72];

    const int tid  = threadIdx.x;
    const int lane = tid & 63;
    const int wave = tid >> 6;
    const int wm   = wave >> 2;
    const int wn   = wave & 3;
    const int l15  = lane & 15;
    const int lg   = lane >> 4;
    const int row0 = blockIdx.x * 64;
    const int e0   = blockIdx.y * 256;

    f32x4 acc[2][4];
    #pragma unroll
    for (int i = 0; i < 2; ++i)
        #pragma unroll
        for (int j = 0; j < 4; ++j)
            acc[i][j] = (f32x4){0.f, 0.f, 0.f, 0.f};

    for (int ko = 0; ko < 128; ko += 64) {
        {
            int r = tid >> 3;         // 0..63
            int c = (tid & 7) * 8;
            bf16x8 v = *reinterpret_cast<const bf16x8*>(att + (size_t)(row0 + r) * 128 + ko + c);
            *reinterpret_cast<bf16x8*>(&As[r][c]) = v;
        }
        {
            int r = tid >> 3;
            int c = (tid & 7) * 8;
            #pragma unroll
            for (int it = 0; it < 4; ++it) {
                bf16x8 v = *reinterpret_cast<const bf16x8*>(Wob + (size_t)(e0 + it * 64 + r) * 128 + ko + c);
                *reinterpret_cast<bf16x8*>(&Bs[it * 64 + r][c]) = v;
            }
        }
        __syncthreads();
        #pragma unroll
        for (int kk = 0; kk < 2; ++kk) {
            bf16x8 af[2], bfr[4];
            #pragma unroll
            for (int mi = 0; mi < 2; ++mi)
                af[mi] = *reinterpret_cast<const bf16x8*>(&As[wm * 32 + mi * 16 + l15][kk * 32 + lg * 8]);
            #pragma unroll
            for (int ni = 0; ni < 4; ++ni)
                bfr[ni] = *reinterpret_cast<const bf16x8*>(&Bs[wn * 64 + ni * 16 + l15][kk * 32 + lg * 8]);
            #pragma unroll
            for (int mi = 0; mi < 2; ++mi)
                #pragma unroll
                for (int ni = 0; ni < 4; ++ni)
                    acc[mi][ni] = __builtin_amdgcn_mfma_f32_16x16x32_bf16(af[mi], bfr[ni], acc[mi][ni], 0, 0, 0);
        }
        __syncthreads();
    }
    #pragma unroll
    for (int mi = 0; mi < 2; ++mi) {
        #pragma unroll
        for (int i = 0; i < 4; ++i) {
            int m = row0 + wm * 32 + mi * 16 + lg * 4 + i;
            #pragma unroll
            for (int ni = 0; ni < 4; ++ni) {
                int e = e0 + wn * 64 + ni * 16 + l15;
                out[(size_t)m * 1024 + e] = acc[mi][ni][i] + bo[e];
            }
        }
    }
}

extern "C" void kernel_launch(void* const* d_in, const int* in_sizes, int n_in,
                              void* d_out, int out_size, void* d_ws, size_t ws_size,
                              hipStream_t stream)
{
    const float* patches     = (const float*)d_in[0];   // [256][196][1024]
    const float* queries     = (const float*)d_in[1];   // [52][128]
    const float* Wk          = (const float*)d_in[2];   // [128][1024]
    const float* Wv          = (const float*)d_in[3];   // [128][1024]
    const float* Wo          = (const float*)d_in[4];   // [1024][128]
    const float* bo          = (const float*)d_in[5];   // [1024]
    const float* patch_pos   = (const float*)d_in[6];   // [196][128]
    const float* temperature = (const float*)d_in[7];   // [1]
    const float* prior       = (const float*)d_in[8];   // [52][196]

    float* out      = (float*)d_out;                    // [256*52][1024]
    float* attn_out = out + (size_t)256 * 52 * 1024;    // [256*52][196]

    unsigned short* Wkvb = (unsigned short*)d_ws;              // 256*1024
    unsigned short* Wob  = Wkvb + 256 * 1024;                  // 1024*128
    unsigned short* kv   = Wob + 1024 * 128;                   // 50176*256
    unsigned short* att  = kv + (size_t)50176 * 256;           // 13312*128
    // ws total: ~29.9 MB

    k_convert <<<512, 256, 0, stream>>>(Wk, Wv, Wo, Wkvb, Wob);
    k_keysvals<<<784, 512, 0, stream>>>(patches, Wkvb, patch_pos, kv);
    k_attn    <<<256, 1024, 0, stream>>>(kv, queries, prior, temperature, attn_out, att);
    k_out     <<<dim3(208, 4), 512, 0, stream>>>(att, Wob, bo, out);
}